// Round 2
// baseline (9669.173 us; speedup 1.0000x reference)
//
#include <hip/hip_runtime.h>
#include <hip/hip_bf16.h>
#include <math.h>

#define LDA 1280   // padded leading dim of A (3N=1233 -> 1280)
#define LDH 512    // padded leading dim of h-like (500 -> 512)
#define LDX 320    // padded leading dim of x/fn (300 -> 320)

__device__ __forceinline__ float arc_sim(float c){
    float cc = c * 0.99999f;
    cc = fminf(1.f, fmaxf(-1.f, cc));
    return 1.f - acosf(cc) * 0.31830988618379067f;  // 1/pi
}

// ---------------- projection + gather (+speaker emb for text) ----------------
__global__ __launch_bounds__(256)
void k_proj(const float* __restrict__ fea, int D,
            const float* __restrict__ W, const float* __restrict__ bias,
            const int* __restrict__ seq, const int* __restrict__ bat,
            const float* __restrict__ speaker, const float* __restrict__ spk_emb,
            float* __restrict__ x, int row0, int N)
{
    __shared__ float sfea[1600];
    __shared__ int sspk;
    int i = blockIdx.x;
    int tid = threadIdx.x;
    int s = seq[i], b = bat[i];
    const float* row = fea + (size_t)(s*12 + b) * D;
    for (int k = tid; k < D; k += 256) sfea[k] = row[k];
    if (speaker != nullptr && tid == 0){
        const float* sp = speaker + (size_t)(s*12 + b) * 9;
        float best = sp[0]; int bi = 0;
        for (int c = 1; c < 9; ++c){ float v = sp[c]; if (v > best){ best = v; bi = c; } }
        sspk = bi;
    }
    __syncthreads();
    for (int h = tid; h < 300; h += 256){
        float acc = bias[h];
        if (speaker != nullptr) acc += spk_emb[sspk*300 + h];
        for (int k = 0; k < D; ++k) acc += sfea[k] * W[(size_t)k*300 + h];
        x[(size_t)(row0 + i)*LDX + h] = acc;
    }
}

// ---------------- row L2 normalize ----------------
__global__ __launch_bounds__(256)
void k_norm(const float* __restrict__ x, float* __restrict__ fn)
{
    __shared__ float red[4];
    int i = blockIdx.x, tid = threadIdx.x;
    float ss = 0.f;
    for (int k = tid; k < 300; k += 256){ float v = x[(size_t)i*LDX + k]; ss += v*v; }
    #pragma unroll
    for (int off = 32; off > 0; off >>= 1) ss += __shfl_down(ss, off, 64);
    if ((tid & 63) == 0) red[tid >> 6] = ss;
    __syncthreads();
    float tot = red[0] + red[1] + red[2] + red[3];
    float inv = 1.f / (sqrtf(tot) + 1e-8f);
    for (int k = tid; k < 300; k += 256) fn[(size_t)i*LDX + k] = x[(size_t)i*LDX + k] * inv;
}

// ---------------- intra-modal adjacency blocks (masked fn_m @ fn_m^T) ----------------
__global__ __launch_bounds__(256)
void k_intra(const float* __restrict__ fn, const int* __restrict__ dia,
             float* __restrict__ A, int N)
{
    int m  = blockIdx.z;
    int i0 = blockIdx.y * 32, j0 = blockIdx.x * 32;
    int iend = min(i0 + 31, N - 1), jend = min(j0 + 31, N - 1);
    // dia_id is non-decreasing -> skip tiles with no same-dialogue pair (A is pre-zeroed)
    if (dia[iend] < dia[j0] || dia[jend] < dia[i0]) return;

    __shared__ float As[32][17], Bs[32][17];
    int tx = threadIdx.x, ty = threadIdx.y;
    int tid = ty*16 + tx;
    float acc[2][2] = {};
    for (int k0 = 0; k0 < 320; k0 += 16){
        __syncthreads();
        for (int l = tid; l < 512; l += 256){
            int r = l >> 4, kk = l & 15;
            int gi = i0 + r, gj = j0 + r;
            As[r][kk] = (gi < N) ? fn[((size_t)m*N + gi)*LDX + k0 + kk] : 0.f;
            Bs[r][kk] = (gj < N) ? fn[((size_t)m*N + gj)*LDX + k0 + kk] : 0.f;
        }
        __syncthreads();
        #pragma unroll
        for (int kk = 0; kk < 16; ++kk){
            float a0 = As[ty*2+0][kk], a1 = As[ty*2+1][kk];
            float b0 = Bs[tx*2+0][kk], b1 = Bs[tx*2+1][kk];
            acc[0][0] += a0*b0; acc[0][1] += a0*b1;
            acc[1][0] += a1*b0; acc[1][1] += a1*b1;
        }
    }
    #pragma unroll
    for (int u = 0; u < 2; ++u)
        #pragma unroll
        for (int v = 0; v < 2; ++v){
            int i = i0 + ty*2 + u, j = j0 + tx*2 + v;
            if (i < N && j < N){
                float val = (dia[i] == dia[j]) ? arc_sim(acc[u][v]) : 0.f;
                A[((size_t)m*N + i)*LDA + (size_t)m*N + j] = val;
            }
        }
}

// ---------------- cross-modal diagonal links ----------------
__global__ void k_cross(const float* __restrict__ fn, float* __restrict__ A, int N)
{
    int i = blockIdx.x, lane = threadIdx.x;
    float d01 = 0.f, d02 = 0.f, d12 = 0.f;
    for (int k = lane; k < 300; k += 64){
        float a = fn[((size_t)0*N + i)*LDX + k];
        float b = fn[((size_t)1*N + i)*LDX + k];
        float c = fn[((size_t)2*N + i)*LDX + k];
        d01 += a*b; d02 += a*c; d12 += b*c;
    }
    #pragma unroll
    for (int off = 32; off > 0; off >>= 1){
        d01 += __shfl_down(d01, off, 64);
        d02 += __shfl_down(d02, off, 64);
        d12 += __shfl_down(d12, off, 64);
    }
    if (lane == 0){
        float s01 = arc_sim(d01), s02 = arc_sim(d02), s12 = arc_sim(d12);
        size_t r0 = i, r1 = (size_t)N + i, r2 = (size_t)2*N + i;
        A[r0*LDA + r1] = s01; A[r1*LDA + r0] = s01;
        A[r0*LDA + r2] = s02; A[r2*LDA + r0] = s02;
        A[r1*LDA + r2] = s12; A[r2*LDA + r1] = s12;
    }
}

// ---------------- degree + D^-1/2 ----------------
__global__ __launch_bounds__(256)
void k_rowsum(const float* __restrict__ A, float* __restrict__ dinv, int M3)
{
    __shared__ float red[4];
    int r = blockIdx.x, tid = threadIdx.x;
    float s = 0.f;
    for (int c = tid; c < M3; c += 256) s += A[(size_t)r*LDA + c];
    #pragma unroll
    for (int off = 32; off > 0; off >>= 1) s += __shfl_down(s, off, 64);
    if ((tid & 63) == 0) red[tid >> 6] = s;
    __syncthreads();
    if (tid == 0){
        float tot = red[0] + red[1] + red[2] + red[3];
        dinv[r] = (tot > 0.f) ? 1.f / sqrtf(tot) : 0.f;
    }
}

__global__ void k_scale(float* __restrict__ A, const float* __restrict__ dinv, int M3)
{
    int c = blockIdx.x*16 + threadIdx.x;
    int r = blockIdx.y*16 + threadIdx.y;
    if (r < M3 && c < M3) A[(size_t)r*LDA + c] *= dinv[r]*dinv[c];
}

// ---------------- h0 = relu(x @ W_in + b_in) ----------------
__global__ __launch_bounds__(256)
void k_gemm_h0(const float* __restrict__ x, const float* __restrict__ Win,
               const float* __restrict__ bin, float* __restrict__ h0, int M3)
{
    __shared__ float As[16][68];
    __shared__ float Bs[16][64];
    int i0 = blockIdx.y*64, j0 = blockIdx.x*64;
    int tid = threadIdx.x;
    int ty = tid >> 4, tx = tid & 15;
    int lr = tid >> 2, lk = (tid & 3) << 2;
    int br = tid >> 4, bc = (tid & 15) << 2;
    float acc[4][4] = {};
    for (int k0 = 0; k0 < 320; k0 += 16){
        float4 av = *(const float4*)&x[(size_t)(i0+lr)*LDX + k0 + lk];
        float4 bwv;
        {
            int kr = k0 + br;
            int c0 = j0 + bc;
            if (kr < 300 && c0 + 3 < 500){
                bwv = *(const float4*)&Win[(size_t)kr*500 + c0];
            } else {
                bwv.x = (kr < 300 && c0+0 < 500) ? Win[(size_t)kr*500 + c0+0] : 0.f;
                bwv.y = (kr < 300 && c0+1 < 500) ? Win[(size_t)kr*500 + c0+1] : 0.f;
                bwv.z = (kr < 300 && c0+2 < 500) ? Win[(size_t)kr*500 + c0+2] : 0.f;
                bwv.w = (kr < 300 && c0+3 < 500) ? Win[(size_t)kr*500 + c0+3] : 0.f;
            }
        }
        __syncthreads();
        As[lk+0][lr] = av.x; As[lk+1][lr] = av.y; As[lk+2][lr] = av.z; As[lk+3][lr] = av.w;
        *(float4*)&Bs[br][bc] = bwv;
        __syncthreads();
        #pragma unroll
        for (int kk = 0; kk < 16; ++kk){
            float4 a4 = *(const float4*)&As[kk][ty*4];
            float4 b4 = *(const float4*)&Bs[kk][tx*4];
            float a_[4] = {a4.x, a4.y, a4.z, a4.w};
            float b_[4] = {b4.x, b4.y, b4.z, b4.w};
            #pragma unroll
            for (int u = 0; u < 4; ++u)
                #pragma unroll
                for (int v = 0; v < 4; ++v) acc[u][v] += a_[u]*b_[v];
        }
    }
    #pragma unroll
    for (int u = 0; u < 4; ++u){
        int i = i0 + ty*4 + u;
        #pragma unroll
        for (int v = 0; v < 4; ++v){
            int j = j0 + tx*4 + v;
            float val = 0.f;
            if (i < M3 && j < 500){
                val = acc[u][v] + bin[j];
                val = fmaxf(val, 0.f);
            }
            h0[(size_t)i*LDH + j] = val;
        }
    }
}

// ---------------- hi = A @ h  (fully padded, guard-free) ----------------
__global__ __launch_bounds__(256)
void k_gemm_A(const float* __restrict__ A, const float* __restrict__ h, float* __restrict__ hi)
{
    __shared__ float As[16][68];
    __shared__ float Bs[16][64];
    int i0 = blockIdx.y*64, j0 = blockIdx.x*64;
    int tid = threadIdx.x;
    int ty = tid >> 4, tx = tid & 15;
    int lr = tid >> 2, lk = (tid & 3) << 2;
    int br = tid >> 4, bc = (tid & 15) << 2;
    float acc[4][4] = {};
    for (int k0 = 0; k0 < 1280; k0 += 16){
        float4 av = *(const float4*)&A[(size_t)(i0+lr)*LDA + k0 + lk];
        float4 bv = *(const float4*)&h[(size_t)(k0+br)*LDH + j0 + bc];
        __syncthreads();
        As[lk+0][lr] = av.x; As[lk+1][lr] = av.y; As[lk+2][lr] = av.z; As[lk+3][lr] = av.w;
        *(float4*)&Bs[br][bc] = bv;
        __syncthreads();
        #pragma unroll
        for (int kk = 0; kk < 16; ++kk){
            float4 a4 = *(const float4*)&As[kk][ty*4];
            float4 b4 = *(const float4*)&Bs[kk][tx*4];
            float a_[4] = {a4.x, a4.y, a4.z, a4.w};
            float b_[4] = {b4.x, b4.y, b4.z, b4.w};
            #pragma unroll
            for (int u = 0; u < 4; ++u)
                #pragma unroll
                for (int v = 0; v < 4; ++v) acc[u][v] += a_[u]*b_[v];
        }
    }
    #pragma unroll
    for (int u = 0; u < 4; ++u){
        int i = i0 + ty*4 + u;
        #pragma unroll
        for (int v = 0; v < 4; ++v)
            hi[(size_t)i*LDH + j0 + tx*4 + v] = acc[u][v];
    }
}

// ---------------- h_next = relu(theta*([hi,h0]@W) + (1-theta)*(0.9*hi + 0.1*h0)) ----------------
__global__ __launch_bounds__(256)
void k_layer(const float* __restrict__ hi, const float* __restrict__ h0,
             const float* __restrict__ W, float theta, float cth,
             float* __restrict__ out)
{
    __shared__ float As[16][68];
    __shared__ float Bs[16][64];
    int i0 = blockIdx.y*64, j0 = blockIdx.x*64;
    int tid = threadIdx.x;
    int ty = tid >> 4, tx = tid & 15;
    int lr = tid >> 2, lk = (tid & 3) << 2;
    int br = tid >> 4, bc = (tid & 15) << 2;
    float acc[4][4] = {};
    for (int k0 = 0; k0 < 1024; k0 += 16){
        const float* src = (k0 < 512) ? hi : h0;
        int ks = (k0 < 512) ? k0 : k0 - 512;
        float4 av = *(const float4*)&src[(size_t)(i0+lr)*LDH + ks + lk];
        float4 bwv;
        {
            int kr = ks + br;                       // 0..511 within half
            int wr = (k0 < 512) ? kr : 500 + kr;    // W row
            int c0 = j0 + bc;
            bool kok = (kr < 500);
            if (kok && c0 + 3 < 500){
                bwv = *(const float4*)&W[(size_t)wr*500 + c0];
            } else {
                bwv.x = (kok && c0+0 < 500) ? W[(size_t)wr*500 + c0+0] : 0.f;
                bwv.y = (kok && c0+1 < 500) ? W[(size_t)wr*500 + c0+1] : 0.f;
                bwv.z = (kok && c0+2 < 500) ? W[(size_t)wr*500 + c0+2] : 0.f;
                bwv.w = (kok && c0+3 < 500) ? W[(size_t)wr*500 + c0+3] : 0.f;
            }
        }
        __syncthreads();
        As[lk+0][lr] = av.x; As[lk+1][lr] = av.y; As[lk+2][lr] = av.z; As[lk+3][lr] = av.w;
        *(float4*)&Bs[br][bc] = bwv;
        __syncthreads();
        #pragma unroll
        for (int kk = 0; kk < 16; ++kk){
            float4 a4 = *(const float4*)&As[kk][ty*4];
            float4 b4 = *(const float4*)&Bs[kk][tx*4];
            float a_[4] = {a4.x, a4.y, a4.z, a4.w};
            float b_[4] = {b4.x, b4.y, b4.z, b4.w};
            #pragma unroll
            for (int u = 0; u < 4; ++u)
                #pragma unroll
                for (int v = 0; v < 4; ++v) acc[u][v] += a_[u]*b_[v];
        }
    }
    #pragma unroll
    for (int u = 0; u < 4; ++u){
        int i = i0 + ty*4 + u;
        float4 hv  = *(const float4*)&hi[(size_t)i*LDH + j0 + tx*4];
        float4 h0v = *(const float4*)&h0[(size_t)i*LDH + j0 + tx*4];
        float4 o;
        o.x = fmaxf(theta*acc[u][0] + cth*(0.9f*hv.x + 0.1f*h0v.x), 0.f);
        o.y = fmaxf(theta*acc[u][1] + cth*(0.9f*hv.y + 0.1f*h0v.y), 0.f);
        o.z = fmaxf(theta*acc[u][2] + cth*(0.9f*hv.z + 0.1f*h0v.z), 0.f);
        o.w = fmaxf(theta*acc[u][3] + cth*(0.9f*hv.w + 0.1f*h0v.w), 0.f);
        *(float4*)&out[(size_t)i*LDH + j0 + tx*4] = o;
    }
}

// ---------------- final classify + log_softmax ----------------
__global__ void k_final(const float* __restrict__ h, const float* __restrict__ Wfc,
                        const float* __restrict__ bfc, float* __restrict__ out,
                        int N)
{
    int i = blockIdx.x, lane = threadIdx.x;  // 64 threads
    float acc[7] = {};
    for (int k = lane; k < 1500; k += 64){
        int m = (k >= 1000) ? 2 : ((k >= 500) ? 1 : 0);
        int kk = k - m*500;
        float f = h[((size_t)m*N + i)*LDH + kk];
        f = fmaxf(f, 0.f);
        #pragma unroll
        for (int c = 0; c < 7; ++c) acc[c] += f * Wfc[(size_t)k*7 + c];
    }
    #pragma unroll
    for (int off = 32; off > 0; off >>= 1){
        #pragma unroll
        for (int c = 0; c < 7; ++c) acc[c] += __shfl_down(acc[c], off, 64);
    }
    if (lane == 0){
        float lg[7], mx = -1e30f;
        #pragma unroll
        for (int c = 0; c < 7; ++c){ lg[c] = acc[c] + bfc[c]; mx = fmaxf(mx, lg[c]); }
        float s = 0.f;
        #pragma unroll
        for (int c = 0; c < 7; ++c) s += expf(lg[c] - mx);
        float lse = mx + logf(s);
        #pragma unroll
        for (int c = 0; c < 7; ++c) out[(size_t)i*7 + c] = lg[c] - lse;
    }
}

extern "C" void kernel_launch(void* const* d_in, const int* in_sizes, int n_in,
                              void* d_out, int out_size, void* d_ws, size_t ws_size,
                              hipStream_t stream)
{
    const float* speaker = (const float*)d_in[1];
    const float* fea_a   = (const float*)d_in[2];
    const float* fea_v   = (const float*)d_in[3];
    const float* fea_t   = (const float*)d_in[4];
    const float* Wa      = (const float*)d_in[5];
    const float* ba      = (const float*)d_in[6];
    const float* Wv      = (const float*)d_in[7];
    const float* bv      = (const float*)d_in[8];
    const float* Wt      = (const float*)d_in[9];
    const float* bt      = (const float*)d_in[10];
    const float* spk_emb = (const float*)d_in[11];
    const float* W_in    = (const float*)d_in[12];
    const float* b_in    = (const float*)d_in[13];
    const float* W_convs = (const float*)d_in[14];
    const float* W_fc1   = (const float*)d_in[15];
    const float* b_fc1   = (const float*)d_in[16];
    const int* seq = (const int*)d_in[18];
    const int* bat = (const int*)d_in[19];
    const int* dia = (const int*)d_in[20];

    const int N  = in_sizes[18];   // 411
    const int M3 = 3*N;            // 1233

    float* ws   = (float*)d_ws;
    float* Aw   = ws;                        // 1280*1280
    float* x    = Aw  + (size_t)LDA*LDA;     // 1280*320
    float* fn   = x   + (size_t)LDA*LDX;     // 1280*320
    float* h0   = fn  + (size_t)LDA*LDX;     // 1280*512
    float* ha   = h0  + (size_t)LDA*LDH;
    float* hb   = ha  + (size_t)LDA*LDH;
    float* hi   = hb  + (size_t)LDA*LDH;
    float* dinv = hi  + (size_t)LDA*LDH;     // 1280

    hipMemsetAsync(Aw, 0, (size_t)LDA*LDA*sizeof(float), stream);
    hipMemsetAsync(x,  0, (size_t)LDA*LDX*sizeof(float), stream);
    hipMemsetAsync(fn, 0, (size_t)LDA*LDX*sizeof(float), stream);

    k_proj<<<N, 256, 0, stream>>>(fea_a, 1582, Wa, ba, seq, bat, nullptr, nullptr, x, 0,   N);
    k_proj<<<N, 256, 0, stream>>>(fea_v,  342, Wv, bv, seq, bat, nullptr, nullptr, x, N,   N);
    k_proj<<<N, 256, 0, stream>>>(fea_t, 1024, Wt, bt, seq, bat, speaker, spk_emb, x, 2*N, N);

    k_norm<<<M3, 256, 0, stream>>>(x, fn);

    int nt = (N + 31)/32;
    k_intra<<<dim3(nt, nt, 3), dim3(16,16), 0, stream>>>(fn, dia, Aw, N);
    k_cross<<<N, 64, 0, stream>>>(fn, Aw, N);
    k_rowsum<<<M3, 256, 0, stream>>>(Aw, dinv, M3);
    k_scale<<<dim3((M3+15)/16, (M3+15)/16), dim3(16,16), 0, stream>>>(Aw, dinv, M3);

    k_gemm_h0<<<dim3(8, 20), 256, 0, stream>>>(x, W_in, b_in, h0, M3);

    const float* cur = h0;
    float* pp[2] = {ha, hb};
    for (int l = 1; l <= 64; ++l){
        k_gemm_A<<<dim3(8, 20), 256, 0, stream>>>(Aw, cur, hi);
        float th = logf(0.5f/(float)l + 1.0f);
        const float* Wl = W_convs + (size_t)(l-1)*1000*500;
        float* o = pp[(l-1) & 1];
        k_layer<<<dim3(8, 20), 256, 0, stream>>>(hi, h0, Wl, th, 1.0f - th, o);
        cur = o;
    }

    k_final<<<N, 64, 0, stream>>>(cur, W_fc1, b_fc1, (float*)d_out, N);
}

// Round 3
// 2201.400 us; speedup vs baseline: 4.3923x; 4.3923x over previous
//
#include <hip/hip_runtime.h>
#include <hip/hip_bf16.h>
#include <math.h>

#define LDA 1280   // padded 3N (1233 -> 1280)
#define LDH 512    // padded G (500 -> 512)
#define LDX 320    // padded H (300 -> 320)

typedef __attribute__((ext_vector_type(8))) short short8;   // 8 bf16 = 4 VGPR (MFMA frag)
typedef __attribute__((ext_vector_type(4))) float f32x4;

__device__ __forceinline__ unsigned short f2b(float x){     // fp32 -> bf16 RNE
    unsigned int u = __float_as_uint(x);
    unsigned int r = (u + 0x7fffu + ((u >> 16) & 1u)) >> 16;
    return (unsigned short)r;
}
__device__ __forceinline__ float b2f(unsigned short u){
    return __uint_as_float(((unsigned int)u) << 16);
}

__device__ __forceinline__ float arc_sim(float c){
    float cc = c * 0.99999f;
    cc = fminf(1.f, fmaxf(-1.f, cc));
    return 1.f - acosf(cc) * 0.31830988618379067f;  // 1/pi
}

// ---------------- gather ragged utterances into padded buffers + speaker idx ----------------
__global__ __launch_bounds__(256)
void k_gather(const float* __restrict__ fa, const float* __restrict__ fv, const float* __restrict__ ft,
              const float* __restrict__ speaker, const int* __restrict__ seq, const int* __restrict__ bat,
              float* __restrict__ xga, float* __restrict__ xgv, float* __restrict__ xgt,
              int* __restrict__ spki, int N)
{
    int i = blockIdx.x;           // 0..447
    int tid = threadIdx.x;
    bool real = i < N;
    int s = real ? seq[i] : 0, b = real ? bat[i] : 0;
    size_t base = (size_t)(s*12 + b);
    for (int k = tid; k < 1600; k += 256) xga[(size_t)i*1600 + k] = (real && k < 1582) ? fa[base*1582 + k] : 0.f;
    for (int k = tid; k < 384;  k += 256) xgv[(size_t)i*384  + k] = (real && k < 342)  ? fv[base*342  + k] : 0.f;
    for (int k = tid; k < 1024; k += 256) xgt[(size_t)i*1024 + k] = real ? ft[base*1024 + k] : 0.f;
    if (tid == 0){
        int bi = 0;
        if (real){
            const float* sp = speaker + base*9;
            float best = sp[0];
            for (int c = 1; c < 9; ++c) if (sp[c] > best){ best = sp[c]; bi = c; }
        }
        spki[i] = bi;
    }
}

// ---------------- projection GEMM: x[row0+i][j] = xg[i]@W + bias (+spk_emb) ----------------
__global__ __launch_bounds__(256)
void k_projg(const float* __restrict__ xg, int Kp, int D,
             const float* __restrict__ W, const float* __restrict__ bias,
             const float* __restrict__ spk_emb, const int* __restrict__ spki,
             float* __restrict__ x, int row0, int N, int useSpk)
{
    __shared__ float As[16][68];
    __shared__ float Bs[16][64];
    int i0 = blockIdx.y*64, j0 = blockIdx.x*64;
    int tid = threadIdx.x;
    int ty = tid >> 4, tx = tid & 15;
    int lr = tid >> 2, lk = (tid & 3) << 2;
    int br = tid >> 4, bc = (tid & 15) << 2;
    float acc[4][4] = {};
    for (int k0 = 0; k0 < Kp; k0 += 16){
        float4 av = *(const float4*)&xg[(size_t)(i0+lr)*Kp + k0 + lk];
        float4 bwv;
        {
            int kr = k0 + br;
            int c0 = j0 + bc;
            if (kr < D && c0 + 3 < 300){
                bwv = *(const float4*)&W[(size_t)kr*300 + c0];
            } else {
                bwv.x = (kr < D && c0+0 < 300) ? W[(size_t)kr*300 + c0+0] : 0.f;
                bwv.y = (kr < D && c0+1 < 300) ? W[(size_t)kr*300 + c0+1] : 0.f;
                bwv.z = (kr < D && c0+2 < 300) ? W[(size_t)kr*300 + c0+2] : 0.f;
                bwv.w = (kr < D && c0+3 < 300) ? W[(size_t)kr*300 + c0+3] : 0.f;
            }
        }
        __syncthreads();
        As[lk+0][lr] = av.x; As[lk+1][lr] = av.y; As[lk+2][lr] = av.z; As[lk+3][lr] = av.w;
        *(float4*)&Bs[br][bc] = bwv;
        __syncthreads();
        #pragma unroll
        for (int kk = 0; kk < 16; ++kk){
            float4 a4 = *(const float4*)&As[kk][ty*4];
            float4 b4 = *(const float4*)&Bs[kk][tx*4];
            float a_[4] = {a4.x, a4.y, a4.z, a4.w};
            float b_[4] = {b4.x, b4.y, b4.z, b4.w};
            #pragma unroll
            for (int u = 0; u < 4; ++u)
                #pragma unroll
                for (int v = 0; v < 4; ++v) acc[u][v] += a_[u]*b_[v];
        }
    }
    #pragma unroll
    for (int u = 0; u < 4; ++u){
        int i = i0 + ty*4 + u;
        if (i >= N) continue;
        #pragma unroll
        for (int v = 0; v < 4; ++v){
            int j = j0 + tx*4 + v;
            float val = 0.f;
            if (j < 300){
                val = acc[u][v] + bias[j];
                if (useSpk) val += spk_emb[spki[i]*300 + j];
            }
            x[(size_t)(row0 + i)*LDX + j] = val;
        }
    }
}

// ---------------- row L2 normalize ----------------
__global__ __launch_bounds__(256)
void k_norm(const float* __restrict__ x, float* __restrict__ fn)
{
    __shared__ float red[4];
    int i = blockIdx.x, tid = threadIdx.x;
    float ss = 0.f;
    for (int k = tid; k < 300; k += 256){ float v = x[(size_t)i*LDX + k]; ss += v*v; }
    #pragma unroll
    for (int off = 32; off > 0; off >>= 1) ss += __shfl_down(ss, off, 64);
    if ((tid & 63) == 0) red[tid >> 6] = ss;
    __syncthreads();
    float tot = red[0] + red[1] + red[2] + red[3];
    float inv = 1.f / (sqrtf(tot) + 1e-8f);
    for (int k = tid; k < 300; k += 256) fn[(size_t)i*LDX + k] = x[(size_t)i*LDX + k] * inv;
}

// ---------------- intra-modal adjacency blocks ----------------
__global__ __launch_bounds__(256)
void k_intra(const float* __restrict__ fn, const int* __restrict__ dia,
             float* __restrict__ A, int N)
{
    int m  = blockIdx.z;
    int i0 = blockIdx.y * 32, j0 = blockIdx.x * 32;
    int iend = min(i0 + 31, N - 1), jend = min(j0 + 31, N - 1);
    if (dia[iend] < dia[j0] || dia[jend] < dia[i0]) return;

    __shared__ float As[32][17], Bs[32][17];
    int tx = threadIdx.x, ty = threadIdx.y;
    int tid = ty*16 + tx;
    float acc[2][2] = {};
    for (int k0 = 0; k0 < 320; k0 += 16){
        __syncthreads();
        for (int l = tid; l < 512; l += 256){
            int r = l >> 4, kk = l & 15;
            int gi = i0 + r, gj = j0 + r;
            As[r][kk] = (gi < N) ? fn[((size_t)m*N + gi)*LDX + k0 + kk] : 0.f;
            Bs[r][kk] = (gj < N) ? fn[((size_t)m*N + gj)*LDX + k0 + kk] : 0.f;
        }
        __syncthreads();
        #pragma unroll
        for (int kk = 0; kk < 16; ++kk){
            float a0 = As[ty*2+0][kk], a1 = As[ty*2+1][kk];
            float b0 = Bs[tx*2+0][kk], b1 = Bs[tx*2+1][kk];
            acc[0][0] += a0*b0; acc[0][1] += a0*b1;
            acc[1][0] += a1*b0; acc[1][1] += a1*b1;
        }
    }
    #pragma unroll
    for (int u = 0; u < 2; ++u)
        #pragma unroll
        for (int v = 0; v < 2; ++v){
            int i = i0 + ty*2 + u, j = j0 + tx*2 + v;
            if (i < N && j < N){
                float val = (dia[i] == dia[j]) ? arc_sim(acc[u][v]) : 0.f;
                A[((size_t)m*N + i)*LDA + (size_t)m*N + j] = val;
            }
        }
}

// ---------------- cross-modal diagonal links ----------------
__global__ void k_cross(const float* __restrict__ fn, float* __restrict__ A, int N)
{
    int i = blockIdx.x, lane = threadIdx.x;
    float d01 = 0.f, d02 = 0.f, d12 = 0.f;
    for (int k = lane; k < 300; k += 64){
        float a = fn[((size_t)0*N + i)*LDX + k];
        float b = fn[((size_t)1*N + i)*LDX + k];
        float c = fn[((size_t)2*N + i)*LDX + k];
        d01 += a*b; d02 += a*c; d12 += b*c;
    }
    #pragma unroll
    for (int off = 32; off > 0; off >>= 1){
        d01 += __shfl_down(d01, off, 64);
        d02 += __shfl_down(d02, off, 64);
        d12 += __shfl_down(d12, off, 64);
    }
    if (lane == 0){
        float s01 = arc_sim(d01), s02 = arc_sim(d02), s12 = arc_sim(d12);
        size_t r0 = i, r1 = (size_t)N + i, r2 = (size_t)2*N + i;
        A[r0*LDA + r1] = s01; A[r1*LDA + r0] = s01;
        A[r0*LDA + r2] = s02; A[r2*LDA + r0] = s02;
        A[r1*LDA + r2] = s12; A[r2*LDA + r1] = s12;
    }
}

// ---------------- degree + D^-1/2 ----------------
__global__ __launch_bounds__(256)
void k_rowsum(const float* __restrict__ A, float* __restrict__ dinv, int M3)
{
    __shared__ float red[4];
    int r = blockIdx.x, tid = threadIdx.x;
    float s = 0.f;
    for (int c = tid; c < M3; c += 256) s += A[(size_t)r*LDA + c];
    #pragma unroll
    for (int off = 32; off > 0; off >>= 1) s += __shfl_down(s, off, 64);
    if ((tid & 63) == 0) red[tid >> 6] = s;
    __syncthreads();
    if (tid == 0){
        float tot = red[0] + red[1] + red[2] + red[3];
        dinv[r] = (tot > 0.f) ? 1.f / sqrtf(tot) : 0.f;
    }
}

// ---------------- scale + bf16 copy of A ----------------
__global__ void k_scale(float* __restrict__ A, unsigned short* __restrict__ Abf,
                        const float* __restrict__ dinv, int M3)
{
    int c = blockIdx.x*16 + threadIdx.x;
    int r = blockIdx.y*16 + threadIdx.y;
    if (r < M3 && c < M3){
        float v = A[(size_t)r*LDA + c] * dinv[r]*dinv[c];
        A[(size_t)r*LDA + c] = v;
        Abf[(size_t)r*LDA + c] = f2b(v);
    }
}

// ---------------- h0 = relu(x @ W_in + b_in); also bf16 + bf16-transposed copies ----------------
__global__ __launch_bounds__(256)
void k_gemm_h0(const float* __restrict__ x, const float* __restrict__ Win,
               const float* __restrict__ bin, float* __restrict__ h0,
               unsigned short* __restrict__ h0b, unsigned short* __restrict__ h0bT, int M3)
{
    __shared__ float As[16][68];
    __shared__ float Bs[16][64];
    int i0 = blockIdx.y*64, j0 = blockIdx.x*64;
    int tid = threadIdx.x;
    int ty = tid >> 4, tx = tid & 15;
    int lr = tid >> 2, lk = (tid & 3) << 2;
    int br = tid >> 4, bc = (tid & 15) << 2;
    float acc[4][4] = {};
    for (int k0 = 0; k0 < 320; k0 += 16){
        float4 av = *(const float4*)&x[(size_t)(i0+lr)*LDX + k0 + lk];
        float4 bwv;
        {
            int kr = k0 + br;
            int c0 = j0 + bc;
            if (kr < 300 && c0 + 3 < 500){
                bwv = *(const float4*)&Win[(size_t)kr*500 + c0];
            } else {
                bwv.x = (kr < 300 && c0+0 < 500) ? Win[(size_t)kr*500 + c0+0] : 0.f;
                bwv.y = (kr < 300 && c0+1 < 500) ? Win[(size_t)kr*500 + c0+1] : 0.f;
                bwv.z = (kr < 300 && c0+2 < 500) ? Win[(size_t)kr*500 + c0+2] : 0.f;
                bwv.w = (kr < 300 && c0+3 < 500) ? Win[(size_t)kr*500 + c0+3] : 0.f;
            }
        }
        __syncthreads();
        As[lk+0][lr] = av.x; As[lk+1][lr] = av.y; As[lk+2][lr] = av.z; As[lk+3][lr] = av.w;
        *(float4*)&Bs[br][bc] = bwv;
        __syncthreads();
        #pragma unroll
        for (int kk = 0; kk < 16; ++kk){
            float4 a4 = *(const float4*)&As[kk][ty*4];
            float4 b4 = *(const float4*)&Bs[kk][tx*4];
            float a_[4] = {a4.x, a4.y, a4.z, a4.w};
            float b_[4] = {b4.x, b4.y, b4.z, b4.w};
            #pragma unroll
            for (int u = 0; u < 4; ++u)
                #pragma unroll
                for (int v = 0; v < 4; ++v) acc[u][v] += a_[u]*b_[v];
        }
    }
    #pragma unroll
    for (int u = 0; u < 4; ++u){
        int i = i0 + ty*4 + u;
        #pragma unroll
        for (int v = 0; v < 4; ++v){
            int j = j0 + tx*4 + v;
            float val = 0.f;
            if (i < M3 && j < 500){
                val = fmaxf(acc[u][v] + bin[j], 0.f);
            }
            h0[(size_t)i*LDH + j] = val;
            unsigned short bv = f2b(val);
            h0b[(size_t)i*LDH + j] = bv;
            h0bT[(size_t)j*LDA + i] = bv;
        }
    }
}

// ---------------- transpose-convert 8 layers of W into rotating bf16 slots ----------------
// grid (16 k-tiles, 8 j-tiles, 8 layers), block 256
__global__ __launch_bounds__(256)
void k_wtr(const float* __restrict__ Wc, int g, unsigned short* __restrict__ Wt)
{
    __shared__ unsigned short sT[64][72];
    int l = g*8 + blockIdx.z;
    int slot = l & 7;
    int k0 = blockIdx.x*64, j0 = blockIdx.y*64;
    const float* W = Wc + (size_t)l*1000*500;
    int t = threadIdx.x;
    #pragma unroll
    for (int rr = 0; rr < 4; ++rr){
        int kl = (t >> 4) + rr*16;
        int k  = k0 + kl;
        int jl = (t & 15) * 4;
        int j  = j0 + jl;
        float4 v;
        if (k < 1000 && j + 3 < 500){
            v = *(const float4*)&W[(size_t)k*500 + j];
        } else {
            v.x = (k < 1000 && j+0 < 500) ? W[(size_t)k*500 + j+0] : 0.f;
            v.y = (k < 1000 && j+1 < 500) ? W[(size_t)k*500 + j+1] : 0.f;
            v.z = (k < 1000 && j+2 < 500) ? W[(size_t)k*500 + j+2] : 0.f;
            v.w = (k < 1000 && j+3 < 500) ? W[(size_t)k*500 + j+3] : 0.f;
        }
        sT[jl+0][kl] = f2b(v.x);
        sT[jl+1][kl] = f2b(v.y);
        sT[jl+2][kl] = f2b(v.z);
        sT[jl+3][kl] = f2b(v.w);
    }
    __syncthreads();
    int jl = t >> 2, kc = (t & 3) * 16;
    unsigned short* dst = Wt + (size_t)slot*LDH*1024 + (size_t)(j0+jl)*1024 + k0 + kc;
    *(uint4*)&dst[0] = *(const uint4*)&sT[jl][kc];
    *(uint4*)&dst[8] = *(const uint4*)&sT[jl][kc+8];
}

#define SWZ(r, k) (((r)*64 + (k)) ^ (((r)&7)<<3))

// ---------------- GEMM1 (MFMA): hi = A @ h  (A_bf row-major, h as bf16-transposed) ----------------
__global__ __launch_bounds__(256)
void k_spmm(const unsigned short* __restrict__ Abf, const unsigned short* __restrict__ hT,
            float* __restrict__ hi, unsigned short* __restrict__ hib)
{
    __shared__ unsigned short sA[64*64], sB[64*64];
    const int i0 = blockIdx.y*64, j0 = blockIdx.x*64;
    const int tid = threadIdx.x, lane = tid & 63, w = tid >> 6;
    const int wr = w >> 1, wc = w & 1;
    const int srow = tid >> 2, scol = (tid & 3) * 16;
    f32x4 acc[2][2] = {};
    for (int k0 = 0; k0 < 1280; k0 += 64){
        uint4 a0 = *(const uint4*)&Abf[(size_t)(i0+srow)*LDA + k0 + scol];
        uint4 a1 = *(const uint4*)&Abf[(size_t)(i0+srow)*LDA + k0 + scol + 8];
        uint4 b0 = *(const uint4*)&hT [(size_t)(j0+srow)*LDA + k0 + scol];
        uint4 b1 = *(const uint4*)&hT [(size_t)(j0+srow)*LDA + k0 + scol + 8];
        __syncthreads();
        *(uint4*)&sA[SWZ(srow, scol)]     = a0;
        *(uint4*)&sA[SWZ(srow, scol + 8)] = a1;
        *(uint4*)&sB[SWZ(srow, scol)]     = b0;
        *(uint4*)&sB[SWZ(srow, scol + 8)] = b1;
        __syncthreads();
        #pragma unroll
        for (int ks = 0; ks < 2; ++ks){
            int kk = ks*32 + (lane >> 4)*8;
            short8 af[2], bfr[2];
            #pragma unroll
            for (int fr = 0; fr < 2; ++fr){
                int r = wr*32 + fr*16 + (lane & 15);
                af[fr] = *(const short8*)&sA[SWZ(r, kk)];
            }
            #pragma unroll
            for (int fc = 0; fc < 2; ++fc){
                int c = wc*32 + fc*16 + (lane & 15);
                bfr[fc] = *(const short8*)&sB[SWZ(c, kk)];
            }
            #pragma unroll
            for (int fr = 0; fr < 2; ++fr)
                #pragma unroll
                for (int fc = 0; fc < 2; ++fc)
                    acc[fr][fc] = __builtin_amdgcn_mfma_f32_16x16x32_bf16(af[fr], bfr[fc], acc[fr][fc], 0, 0, 0);
        }
    }
    #pragma unroll
    for (int fr = 0; fr < 2; ++fr)
        #pragma unroll
        for (int fc = 0; fc < 2; ++fc)
            #pragma unroll
            for (int rg = 0; rg < 4; ++rg){
                int i = i0 + wr*32 + fr*16 + (lane >> 4)*4 + rg;
                int j = j0 + wc*32 + fc*16 + (lane & 15);
                float v = acc[fr][fc][rg];
                hi [(size_t)i*LDH + j] = v;
                hib[(size_t)i*LDH + j] = f2b(v);
            }
}

// ---------------- GEMM2 (MFMA) + GCNII epilogue; writes h_next as bf16-transposed ----------------
__global__ __launch_bounds__(256)
void k_layerm(const unsigned short* __restrict__ hib, const unsigned short* __restrict__ h0b,
              const unsigned short* __restrict__ Wt, const float* __restrict__ hi,
              const float* __restrict__ h0, float theta, float cth,
              unsigned short* __restrict__ hT_out)
{
    __shared__ unsigned short sA[64*64], sB[64*64];
    const int i0 = blockIdx.y*64, j0 = blockIdx.x*64;
    const int tid = threadIdx.x, lane = tid & 63, w = tid >> 6;
    const int wr = w >> 1, wc = w & 1;
    const int srow = tid >> 2, scol = (tid & 3) * 16;
    f32x4 acc[2][2] = {};
    for (int k0 = 0; k0 < 1024; k0 += 64){
        const unsigned short* asrc = (k0 < 512) ? &hib[(size_t)(i0+srow)*LDH + k0]
                                                : &h0b[(size_t)(i0+srow)*LDH + k0 - 512];
        uint4 a0 = *(const uint4*)&asrc[scol];
        uint4 a1 = *(const uint4*)&asrc[scol + 8];
        uint4 b0 = *(const uint4*)&Wt[(size_t)(j0+srow)*1024 + k0 + scol];
        uint4 b1 = *(const uint4*)&Wt[(size_t)(j0+srow)*1024 + k0 + scol + 8];
        __syncthreads();
        *(uint4*)&sA[SWZ(srow, scol)]     = a0;
        *(uint4*)&sA[SWZ(srow, scol + 8)] = a1;
        *(uint4*)&sB[SWZ(srow, scol)]     = b0;
        *(uint4*)&sB[SWZ(srow, scol + 8)] = b1;
        __syncthreads();
        #pragma unroll
        for (int ks = 0; ks < 2; ++ks){
            int kk = ks*32 + (lane >> 4)*8;
            short8 af[2], bfr[2];
            #pragma unroll
            for (int fr = 0; fr < 2; ++fr){
                int r = wr*32 + fr*16 + (lane & 15);
                af[fr] = *(const short8*)&sA[SWZ(r, kk)];
            }
            #pragma unroll
            for (int fc = 0; fc < 2; ++fc){
                int c = wc*32 + fc*16 + (lane & 15);
                bfr[fc] = *(const short8*)&sB[SWZ(c, kk)];
            }
            #pragma unroll
            for (int fr = 0; fr < 2; ++fr)
                #pragma unroll
                for (int fc = 0; fc < 2; ++fc)
                    acc[fr][fc] = __builtin_amdgcn_mfma_f32_16x16x32_bf16(af[fr], bfr[fc], acc[fr][fc], 0, 0, 0);
        }
    }
    #pragma unroll
    for (int fr = 0; fr < 2; ++fr)
        #pragma unroll
        for (int fc = 0; fc < 2; ++fc)
            #pragma unroll
            for (int rg = 0; rg < 4; ++rg){
                int i = i0 + wr*32 + fr*16 + (lane >> 4)*4 + rg;
                int j = j0 + wc*32 + fc*16 + (lane & 15);
                float hv  = hi[(size_t)i*LDH + j];
                float h0v = h0[(size_t)i*LDH + j];
                float o = fmaxf(theta*acc[fr][fc][rg] + cth*(0.9f*hv + 0.1f*h0v), 0.f);
                hT_out[(size_t)j*LDA + i] = f2b(o);
            }
}

// ---------------- final classify + log_softmax (reads bf16-transposed h) ----------------
__global__ void k_final(const unsigned short* __restrict__ hT, const float* __restrict__ Wfc,
                        const float* __restrict__ bfc, float* __restrict__ out, int N)
{
    int i = blockIdx.x, lane = threadIdx.x;  // 64 threads
    float acc[7] = {};
    for (int k = lane; k < 1500; k += 64){
        int m = (k >= 1000) ? 2 : ((k >= 500) ? 1 : 0);
        int kk = k - m*500;
        float f = b2f(hT[(size_t)kk*LDA + m*N + i]);
        f = fmaxf(f, 0.f);
        #pragma unroll
        for (int c = 0; c < 7; ++c) acc[c] += f * Wfc[(size_t)k*7 + c];
    }
    #pragma unroll
    for (int off = 32; off > 0; off >>= 1){
        #pragma unroll
        for (int c = 0; c < 7; ++c) acc[c] += __shfl_down(acc[c], off, 64);
    }
    if (lane == 0){
        float lg[7], mx = -1e30f;
        #pragma unroll
        for (int c = 0; c < 7; ++c){ lg[c] = acc[c] + bfc[c]; mx = fmaxf(mx, lg[c]); }
        float s = 0.f;
        #pragma unroll
        for (int c = 0; c < 7; ++c) s += expf(lg[c] - mx);
        float lse = mx + logf(s);
        #pragma unroll
        for (int c = 0; c < 7; ++c) out[(size_t)i*7 + c] = lg[c] - lse;
    }
}

extern "C" void kernel_launch(void* const* d_in, const int* in_sizes, int n_in,
                              void* d_out, int out_size, void* d_ws, size_t ws_size,
                              hipStream_t stream)
{
    const float* speaker = (const float*)d_in[1];
    const float* fea_a   = (const float*)d_in[2];
    const float* fea_v   = (const float*)d_in[3];
    const float* fea_t   = (const float*)d_in[4];
    const float* Wa      = (const float*)d_in[5];
    const float* ba      = (const float*)d_in[6];
    const float* Wv      = (const float*)d_in[7];
    const float* bv      = (const float*)d_in[8];
    const float* Wt_in   = (const float*)d_in[9];
    const float* bt      = (const float*)d_in[10];
    const float* spk_emb = (const float*)d_in[11];
    const float* W_in    = (const float*)d_in[12];
    const float* b_in    = (const float*)d_in[13];
    const float* W_convs = (const float*)d_in[14];
    const float* W_fc1   = (const float*)d_in[15];
    const float* b_fc1   = (const float*)d_in[16];
    const int* seq = (const int*)d_in[18];
    const int* bat = (const int*)d_in[19];
    const int* dia = (const int*)d_in[20];

    const int N  = in_sizes[18];   // 411
    const int M3 = 3*N;            // 1233

    // ---- workspace layout (byte offsets) ----
    char* wsb = (char*)d_ws;
    float*          Aw   = (float*)(wsb);                               // 6,553,600 B
    unsigned short* Abf  = (unsigned short*)(wsb + 6553600);            // 3,276,800
    float*          x    = (float*)(wsb + 9830400);                     // 1,638,400
    float*          fn   = (float*)(wsb + 11468800);                    // 1,638,400
    float*          h0   = (float*)(wsb + 13107200);                    // 2,621,440
    unsigned short* h0b  = (unsigned short*)(wsb + 15728640);           // 1,310,720
    unsigned short* h0bT = (unsigned short*)(wsb + 17039360);           // 1,310,720
    unsigned short* hTa  = (unsigned short*)(wsb + 18350080);           // 1,310,720
    unsigned short* hTb  = (unsigned short*)(wsb + 19660800);           // 1,310,720
    float*          hi   = (float*)(wsb + 20971520);                    // 2,621,440
    unsigned short* hib  = (unsigned short*)(wsb + 23592960);           // 1,310,720
    unsigned short* Wt   = (unsigned short*)(wsb + 24903680);           // 8,388,608 (8 slots)
    float*          dinv = (float*)(wsb + 33292288);                    // 5,120
    float*          xga  = (float*)(wsb + 33297408);                    // 2,867,200
    float*          xgv  = (float*)(wsb + 36164608);                    // 688,128
    float*          xgt  = (float*)(wsb + 36852736);                    // 1,835,008
    int*            spki = (int*)(wsb + 38687744);                      // 1,792

    hipMemsetAsync(Aw,  0, 6553600, stream);
    hipMemsetAsync(Abf, 0, 3276800, stream);
    hipMemsetAsync(x,   0, 1638400, stream);
    hipMemsetAsync(fn,  0, 1638400, stream);

    k_gather<<<448, 256, 0, stream>>>(fea_a, fea_v, fea_t, speaker, seq, bat, xga, xgv, xgt, spki, N);

    k_projg<<<dim3(5,7), 256, 0, stream>>>(xga, 1600, 1582, Wa, ba, spk_emb, spki, x, 0,   N, 0);
    k_projg<<<dim3(5,7), 256, 0, stream>>>(xgv,  384,  342, Wv, bv, spk_emb, spki, x, N,   N, 0);
    k_projg<<<dim3(5,7), 256, 0, stream>>>(xgt, 1024, 1024, Wt_in, bt, spk_emb, spki, x, 2*N, N, 1);

    k_norm<<<M3, 256, 0, stream>>>(x, fn);

    int nt = (N + 31)/32;
    k_intra<<<dim3(nt, nt, 3), dim3(16,16), 0, stream>>>(fn, dia, Aw, N);
    k_cross<<<N, 64, 0, stream>>>(fn, Aw, N);
    k_rowsum<<<M3, 256, 0, stream>>>(Aw, dinv, M3);
    k_scale<<<dim3((M3+15)/16, (M3+15)/16), dim3(16,16), 0, stream>>>(Aw, Abf, dinv, M3);

    k_gemm_h0<<<dim3(8, 20), 256, 0, stream>>>(x, W_in, b_in, h0, h0b, h0bT, M3);

    const unsigned short* curT = h0bT;
    unsigned short* pp[2] = {hTa, hTb};
    for (int l = 1; l <= 64; ++l){
        if (((l-1) & 7) == 0)
            k_wtr<<<dim3(16, 8, 8), 256, 0, stream>>>(W_convs, (l-1) >> 3, Wt);
        k_spmm<<<dim3(8, 20), 256, 0, stream>>>(Abf, curT, hi, hib);
        float th = logf(0.5f/(float)l + 1.0f);
        unsigned short* o = pp[(l-1) & 1];
        k_layerm<<<dim3(8, 20), 256, 0, stream>>>(hib, h0b, Wt + (size_t)((l-1) & 7)*LDH*1024,
                                                  hi, h0, th, 1.0f - th, o);
        curT = o;
    }

    k_final<<<N, 64, 0, stream>>>(curT, W_fc1, b_fc1, (float*)d_out, N);
}

// Round 4
// 1339.753 us; speedup vs baseline: 7.2171x; 1.6431x over previous
//
#include <hip/hip_runtime.h>
#include <hip/hip_bf16.h>
#include <math.h>

#define LDA 1280   // padded 3N (1233 -> 1280)
#define LDH 512    // padded G (500 -> 512)
#define LDX 320    // padded H (300 -> 320)

typedef __attribute__((ext_vector_type(8))) short short8;   // 8 bf16 = 4 VGPR (MFMA frag)
typedef __attribute__((ext_vector_type(4))) float f32x4;

__device__ __forceinline__ unsigned short f2b(float x){     // fp32 -> bf16 RNE
    unsigned int u = __float_as_uint(x);
    unsigned int r = (u + 0x7fffu + ((u >> 16) & 1u)) >> 16;
    return (unsigned short)r;
}
__device__ __forceinline__ float b2f(unsigned short u){
    return __uint_as_float(((unsigned int)u) << 16);
}

__device__ __forceinline__ float arc_sim(float c){
    float cc = c * 0.99999f;
    cc = fminf(1.f, fmaxf(-1.f, cc));
    return 1.f - acosf(cc) * 0.31830988618379067f;  // 1/pi
}

// ---------------- gather ragged utterances into padded buffers + speaker idx ----------------
__global__ __launch_bounds__(256)
void k_gather(const float* __restrict__ fa, const float* __restrict__ fv, const float* __restrict__ ft,
              const float* __restrict__ speaker, const int* __restrict__ seq, const int* __restrict__ bat,
              float* __restrict__ xga, float* __restrict__ xgv, float* __restrict__ xgt,
              int* __restrict__ spki, int N)
{
    int i = blockIdx.x;           // 0..447
    int tid = threadIdx.x;
    bool real = i < N;
    int s = real ? seq[i] : 0, b = real ? bat[i] : 0;
    size_t base = (size_t)(s*12 + b);
    for (int k = tid; k < 1600; k += 256) xga[(size_t)i*1600 + k] = (real && k < 1582) ? fa[base*1582 + k] : 0.f;
    for (int k = tid; k < 384;  k += 256) xgv[(size_t)i*384  + k] = (real && k < 342)  ? fv[base*342  + k] : 0.f;
    for (int k = tid; k < 1024; k += 256) xgt[(size_t)i*1024 + k] = real ? ft[base*1024 + k] : 0.f;
    if (tid == 0){
        int bi = 0;
        if (real){
            const float* sp = speaker + base*9;
            float best = sp[0];
            for (int c = 1; c < 9; ++c) if (sp[c] > best){ best = sp[c]; bi = c; }
        }
        spki[i] = bi;
    }
}

// ---------------- transpose projection weight W[D][300] -> WT[300][Kp] fp32 (zero-padded) ---
__global__ __launch_bounds__(256)
void k_trw(const float* __restrict__ W, int D, int Kp, float* __restrict__ WTr)
{
    __shared__ float tt[64][65];
    int k0 = blockIdx.x*64, j0 = blockIdx.y*64;
    int t = threadIdx.x;
    #pragma unroll
    for (int rr = 0; rr < 4; ++rr){
        int kl = (t >> 4) + rr*16;
        int k  = k0 + kl;
        int jl = (t & 15) * 4;
        int j  = j0 + jl;
        float4 v;
        if (k < D && j + 3 < 300){
            v = *(const float4*)&W[(size_t)k*300 + j];
        } else {
            v.x = (k < D && j+0 < 300) ? W[(size_t)k*300 + j+0] : 0.f;
            v.y = (k < D && j+1 < 300) ? W[(size_t)k*300 + j+1] : 0.f;
            v.z = (k < D && j+2 < 300) ? W[(size_t)k*300 + j+2] : 0.f;
            v.w = (k < D && j+3 < 300) ? W[(size_t)k*300 + j+3] : 0.f;
        }
        tt[jl+0][kl] = v.x; tt[jl+1][kl] = v.y; tt[jl+2][kl] = v.z; tt[jl+3][kl] = v.w;
    }
    __syncthreads();
    #pragma unroll
    for (int rr = 0; rr < 4; ++rr){
        int jl = (t >> 4) + rr*16;
        int j  = j0 + jl;
        int kq = (t & 15) * 4;
        if (j < 300){
            float4 o; o.x = tt[jl][kq]; o.y = tt[jl][kq+1]; o.z = tt[jl][kq+2]; o.w = tt[jl][kq+3];
            *(float4*)&WTr[(size_t)j*Kp + k0 + kq] = o;
        }
    }
}

// ---------------- projection GEMM partials (split-K): xp[z][448][320] = xg @ WT^T slice ------
__global__ __launch_bounds__(256)
void k_projg2(const float* __restrict__ xg, int Kp, int kslice,
              const float* __restrict__ WTr,      // [300][Kp]
              float* __restrict__ xp)             // [KS][448][320]
{
    __shared__ float As[16][68];
    __shared__ float Bs[16][64];
    int i0 = blockIdx.y*64, j0 = blockIdx.x*64;
    int ks0 = blockIdx.z * kslice;
    int tid = threadIdx.x;
    int ty = tid >> 4, tx = tid & 15;
    int lr = tid >> 2, lk = (tid & 3) << 2;
    int bj = tid & 63, bk4 = (tid >> 6) << 2;
    float acc[4][4] = {};
    for (int k0 = 0; k0 < kslice; k0 += 16){
        float4 av = *(const float4*)&xg[(size_t)(i0+lr)*Kp + ks0 + k0 + lk];
        float4 wv = {0.f, 0.f, 0.f, 0.f};
        int j = j0 + bj;
        if (j < 300) wv = *(const float4*)&WTr[(size_t)j*Kp + ks0 + k0 + bk4];
        __syncthreads();
        As[lk+0][lr] = av.x; As[lk+1][lr] = av.y; As[lk+2][lr] = av.z; As[lk+3][lr] = av.w;
        Bs[bk4+0][bj] = wv.x; Bs[bk4+1][bj] = wv.y; Bs[bk4+2][bj] = wv.z; Bs[bk4+3][bj] = wv.w;
        __syncthreads();
        #pragma unroll
        for (int kk = 0; kk < 16; ++kk){
            float4 a4 = *(const float4*)&As[kk][ty*4];
            float4 b4 = *(const float4*)&Bs[kk][tx*4];
            float a_[4] = {a4.x, a4.y, a4.z, a4.w};
            float b_[4] = {b4.x, b4.y, b4.z, b4.w};
            #pragma unroll
            for (int u = 0; u < 4; ++u)
                #pragma unroll
                for (int v = 0; v < 4; ++v) acc[u][v] += a_[u]*b_[v];
        }
    }
    #pragma unroll
    for (int u = 0; u < 4; ++u){
        int i = i0 + ty*4 + u;
        #pragma unroll
        for (int v = 0; v < 4; ++v){
            int j = j0 + tx*4 + v;
            xp[((size_t)blockIdx.z*448 + i)*320 + j] = acc[u][v];
        }
    }
}

// ---------------- reduce split-K partials + bias + spk, write x and fn (L2 norm) ------------
__global__ __launch_bounds__(256)
void k_norm2(const float* __restrict__ xpa, const float* __restrict__ xpv, const float* __restrict__ xpt,
             const float* __restrict__ ba, const float* __restrict__ bv, const float* __restrict__ bt,
             const float* __restrict__ spk_emb, const int* __restrict__ spki,
             float* __restrict__ x, float* __restrict__ fn, int N)
{
    __shared__ float red[4];
    int r = blockIdx.x, tid = threadIdx.x;
    int m = (r >= 2*N) ? 2 : (r >= N ? 1 : 0);
    int n = r - m*N;
    const float* xp   = (m==0) ? xpa : (m==1) ? xpv : xpt;
    const float* bias = (m==0) ? ba  : (m==1) ? bv  : bt;
    int KS = (m==1) ? 2 : 4;
    float v0 = 0.f, v1 = 0.f;
    int j0 = tid, j1 = tid + 256;
    if (j0 < 300){
        float s = bias[j0];
        for (int si = 0; si < KS; ++si) s += xp[((size_t)si*448 + n)*320 + j0];
        if (m == 2) s += spk_emb[spki[n]*300 + j0];
        v0 = s;
    }
    if (j1 < 300){
        float s = bias[j1];
        for (int si = 0; si < KS; ++si) s += xp[((size_t)si*448 + n)*320 + j1];
        if (m == 2) s += spk_emb[spki[n]*300 + j1];
        v1 = s;
    }
    float ss = v0*v0 + v1*v1;
    #pragma unroll
    for (int off = 32; off > 0; off >>= 1) ss += __shfl_down(ss, off, 64);
    if ((tid & 63) == 0) red[tid >> 6] = ss;
    __syncthreads();
    float tot = red[0] + red[1] + red[2] + red[3];
    float inv = 1.f / (sqrtf(tot) + 1e-8f);
    x [(size_t)r*LDX + j0] = v0;
    fn[(size_t)r*LDX + j0] = v0 * inv;
    if (j1 < 320){
        x [(size_t)r*LDX + j1] = v1;
        fn[(size_t)r*LDX + j1] = v1 * inv;
    }
}

// ---------------- intra-modal adjacency blocks ----------------
__global__ __launch_bounds__(256)
void k_intra(const float* __restrict__ fn, const int* __restrict__ dia,
             float* __restrict__ A, int N)
{
    int m  = blockIdx.z;
    int i0 = blockIdx.y * 32, j0 = blockIdx.x * 32;
    int iend = min(i0 + 31, N - 1), jend = min(j0 + 31, N - 1);
    if (dia[iend] < dia[j0] || dia[jend] < dia[i0]) return;

    __shared__ float As[32][17], Bs[32][17];
    int tx = threadIdx.x, ty = threadIdx.y;
    int tid = ty*16 + tx;
    float acc[2][2] = {};
    for (int k0 = 0; k0 < 320; k0 += 16){
        __syncthreads();
        for (int l = tid; l < 512; l += 256){
            int r = l >> 4, kk = l & 15;
            int gi = i0 + r, gj = j0 + r;
            As[r][kk] = (gi < N) ? fn[((size_t)m*N + gi)*LDX + k0 + kk] : 0.f;
            Bs[r][kk] = (gj < N) ? fn[((size_t)m*N + gj)*LDX + k0 + kk] : 0.f;
        }
        __syncthreads();
        #pragma unroll
        for (int kk = 0; kk < 16; ++kk){
            float a0 = As[ty*2+0][kk], a1 = As[ty*2+1][kk];
            float b0 = Bs[tx*2+0][kk], b1 = Bs[tx*2+1][kk];
            acc[0][0] += a0*b0; acc[0][1] += a0*b1;
            acc[1][0] += a1*b0; acc[1][1] += a1*b1;
        }
    }
    #pragma unroll
    for (int u = 0; u < 2; ++u)
        #pragma unroll
        for (int v = 0; v < 2; ++v){
            int i = i0 + ty*2 + u, j = j0 + tx*2 + v;
            if (i < N && j < N){
                float val = (dia[i] == dia[j]) ? arc_sim(acc[u][v]) : 0.f;
                A[((size_t)m*N + i)*LDA + (size_t)m*N + j] = val;
            }
        }
}

// ---------------- cross-modal diagonal links ----------------
__global__ void k_cross(const float* __restrict__ fn, float* __restrict__ A, int N)
{
    int i = blockIdx.x, lane = threadIdx.x;
    float d01 = 0.f, d02 = 0.f, d12 = 0.f;
    for (int k = lane; k < 300; k += 64){
        float a = fn[((size_t)0*N + i)*LDX + k];
        float b = fn[((size_t)1*N + i)*LDX + k];
        float c = fn[((size_t)2*N + i)*LDX + k];
        d01 += a*b; d02 += a*c; d12 += b*c;
    }
    #pragma unroll
    for (int off = 32; off > 0; off >>= 1){
        d01 += __shfl_down(d01, off, 64);
        d02 += __shfl_down(d02, off, 64);
        d12 += __shfl_down(d12, off, 64);
    }
    if (lane == 0){
        float s01 = arc_sim(d01), s02 = arc_sim(d02), s12 = arc_sim(d12);
        size_t r0 = i, r1 = (size_t)N + i, r2 = (size_t)2*N + i;
        A[r0*LDA + r1] = s01; A[r1*LDA + r0] = s01;
        A[r0*LDA + r2] = s02; A[r2*LDA + r0] = s02;
        A[r1*LDA + r2] = s12; A[r2*LDA + r1] = s12;
    }
}

// ---------------- degree + D^-1/2 ----------------
__global__ __launch_bounds__(256)
void k_rowsum(const float* __restrict__ A, float* __restrict__ dinv, int M3)
{
    __shared__ float red[4];
    int r = blockIdx.x, tid = threadIdx.x;
    float s = 0.f;
    for (int c = tid; c < M3; c += 256) s += A[(size_t)r*LDA + c];
    #pragma unroll
    for (int off = 32; off > 0; off >>= 1) s += __shfl_down(s, off, 64);
    if ((tid & 63) == 0) red[tid >> 6] = s;
    __syncthreads();
    if (tid == 0){
        float tot = red[0] + red[1] + red[2] + red[3];
        dinv[r] = (tot > 0.f) ? 1.f / sqrtf(tot) : 0.f;
    }
}

// ---------------- scale + bf16 copy of A ----------------
__global__ void k_scale(float* __restrict__ A, unsigned short* __restrict__ Abf,
                        const float* __restrict__ dinv, int M3)
{
    int c = blockIdx.x*16 + threadIdx.x;
    int r = blockIdx.y*16 + threadIdx.y;
    if (r < M3 && c < M3){
        float v = A[(size_t)r*LDA + c] * dinv[r]*dinv[c];
        A[(size_t)r*LDA + c] = v;
        Abf[(size_t)r*LDA + c] = f2b(v);
    }
}

// ---------------- h0 = relu(x @ W_in + b_in); also bf16 + bf16-transposed copies ----------------
__global__ __launch_bounds__(256)
void k_gemm_h0(const float* __restrict__ x, const float* __restrict__ Win,
               const float* __restrict__ bin, float* __restrict__ h0,
               unsigned short* __restrict__ h0b, unsigned short* __restrict__ h0bT, int M3)
{
    __shared__ float As[16][68];
    __shared__ float Bs[16][64];
    int i0 = blockIdx.y*64, j0 = blockIdx.x*64;
    int tid = threadIdx.x;
    int ty = tid >> 4, tx = tid & 15;
    int lr = tid >> 2, lk = (tid & 3) << 2;
    int br = tid >> 4, bc = (tid & 15) << 2;
    float acc[4][4] = {};
    for (int k0 = 0; k0 < 320; k0 += 16){
        float4 av = *(const float4*)&x[(size_t)(i0+lr)*LDX + k0 + lk];
        float4 bwv;
        {
            int kr = k0 + br;
            int c0 = j0 + bc;
            if (kr < 300 && c0 + 3 < 500){
                bwv = *(const float4*)&Win[(size_t)kr*500 + c0];
            } else {
                bwv.x = (kr < 300 && c0+0 < 500) ? Win[(size_t)kr*500 + c0+0] : 0.f;
                bwv.y = (kr < 300 && c0+1 < 500) ? Win[(size_t)kr*500 + c0+1] : 0.f;
                bwv.z = (kr < 300 && c0+2 < 500) ? Win[(size_t)kr*500 + c0+2] : 0.f;
                bwv.w = (kr < 300 && c0+3 < 500) ? Win[(size_t)kr*500 + c0+3] : 0.f;
            }
        }
        __syncthreads();
        As[lk+0][lr] = av.x; As[lk+1][lr] = av.y; As[lk+2][lr] = av.z; As[lk+3][lr] = av.w;
        *(float4*)&Bs[br][bc] = bwv;
        __syncthreads();
        #pragma unroll
        for (int kk = 0; kk < 16; ++kk){
            float4 a4 = *(const float4*)&As[kk][ty*4];
            float4 b4 = *(const float4*)&Bs[kk][tx*4];
            float a_[4] = {a4.x, a4.y, a4.z, a4.w};
            float b_[4] = {b4.x, b4.y, b4.z, b4.w};
            #pragma unroll
            for (int u = 0; u < 4; ++u)
                #pragma unroll
                for (int v = 0; v < 4; ++v) acc[u][v] += a_[u]*b_[v];
        }
    }
    #pragma unroll
    for (int u = 0; u < 4; ++u){
        int i = i0 + ty*4 + u;
        #pragma unroll
        for (int v = 0; v < 4; ++v){
            int j = j0 + tx*4 + v;
            float val = 0.f;
            if (i < M3 && j < 500){
                val = fmaxf(acc[u][v] + bin[j], 0.f);
            }
            h0[(size_t)i*LDH + j] = val;
            unsigned short bv = f2b(val);
            h0b[(size_t)i*LDH + j] = bv;
            h0bT[(size_t)j*LDA + i] = bv;
        }
    }
}

// ---------------- transpose-convert 8 layers of W into rotating bf16 slots ------------------
// FIXED mapping: WT[j][k] = W[k][j] for k<500 (hi part); WT[j][512+t] = W[500+t][j] (h0 part)
__global__ __launch_bounds__(256)
void k_wtr(const float* __restrict__ Wc, int g, unsigned short* __restrict__ Wt)
{
    __shared__ unsigned short sT[64][72];
    int l = g*8 + blockIdx.z;
    int slot = l & 7;
    int k0 = blockIdx.x*64, j0 = blockIdx.y*64;   // k0 = OUTPUT col tile
    const float* W = Wc + (size_t)l*1000*500;
    int ksrc0 = (k0 < 512) ? k0 : k0 - 12;
    int klim  = (k0 < 512) ? 500 : 1000;
    int t = threadIdx.x;
    #pragma unroll
    for (int rr = 0; rr < 4; ++rr){
        int kl = (t >> 4) + rr*16;
        int k  = ksrc0 + kl;                      // source W row
        int jl = (t & 15) * 4;
        int j  = j0 + jl;
        bool vk = (k < klim);
        float4 v;
        if (vk && j + 3 < 500){
            v = *(const float4*)&W[(size_t)k*500 + j];
        } else {
            v.x = (vk && j+0 < 500) ? W[(size_t)k*500 + j+0] : 0.f;
            v.y = (vk && j+1 < 500) ? W[(size_t)k*500 + j+1] : 0.f;
            v.z = (vk && j+2 < 500) ? W[(size_t)k*500 + j+2] : 0.f;
            v.w = (vk && j+3 < 500) ? W[(size_t)k*500 + j+3] : 0.f;
        }
        sT[jl+0][kl] = f2b(v.x);
        sT[jl+1][kl] = f2b(v.y);
        sT[jl+2][kl] = f2b(v.z);
        sT[jl+3][kl] = f2b(v.w);
    }
    __syncthreads();
    int jl = t >> 2, kc = (t & 3) * 16;
    unsigned short* dst = Wt + (size_t)slot*LDH*1024 + (size_t)(j0+jl)*1024 + k0 + kc;
    *(uint4*)&dst[0] = *(const uint4*)&sT[jl][kc];
    *(uint4*)&dst[8] = *(const uint4*)&sT[jl][kc+8];
}

#define SWZ(r, k) (((r)*64 + (k)) ^ (((r)&7)<<3))

// ---------------- GEMM1 (MFMA, reg-prefetch): hi = A @ h ----------------
__global__ __launch_bounds__(256)
void k_spmm(const unsigned short* __restrict__ Abf, const unsigned short* __restrict__ hT,
            float* __restrict__ hi, unsigned short* __restrict__ hib)
{
    __shared__ unsigned short sA[64*64], sB[64*64];
    const int i0 = blockIdx.y*64, j0 = blockIdx.x*64;
    const int tid = threadIdx.x, lane = tid & 63, w = tid >> 6;
    const int wr = w >> 1, wc = w & 1;
    const int srow = tid >> 2, scol = (tid & 3) * 16;
    const unsigned short* pa = &Abf[(size_t)(i0+srow)*LDA + scol];
    const unsigned short* pb = &hT [(size_t)(j0+srow)*LDA + scol];
    uint4 a0 = *(const uint4*)(pa);
    uint4 a1 = *(const uint4*)(pa + 8);
    uint4 b0 = *(const uint4*)(pb);
    uint4 b1 = *(const uint4*)(pb + 8);
    f32x4 acc[2][2] = {};
    for (int k0 = 0; k0 < 1280; k0 += 64){
        *(uint4*)&sA[SWZ(srow, scol)]     = a0;
        *(uint4*)&sA[SWZ(srow, scol + 8)] = a1;
        *(uint4*)&sB[SWZ(srow, scol)]     = b0;
        *(uint4*)&sB[SWZ(srow, scol + 8)] = b1;
        if (k0 + 64 < 1280){
            a0 = *(const uint4*)(pa + k0 + 64);
            a1 = *(const uint4*)(pa + k0 + 72);
            b0 = *(const uint4*)(pb + k0 + 64);
            b1 = *(const uint4*)(pb + k0 + 72);
        }
        __syncthreads();
        #pragma unroll
        for (int ks = 0; ks < 2; ++ks){
            int kk = ks*32 + (lane >> 4)*8;
            short8 af[2], bfr[2];
            #pragma unroll
            for (int fr = 0; fr < 2; ++fr){
                int r = wr*32 + fr*16 + (lane & 15);
                af[fr] = *(const short8*)&sA[SWZ(r, kk)];
            }
            #pragma unroll
            for (int fc = 0; fc < 2; ++fc){
                int c = wc*32 + fc*16 + (lane & 15);
                bfr[fc] = *(const short8*)&sB[SWZ(c, kk)];
            }
            #pragma unroll
            for (int fr = 0; fr < 2; ++fr)
                #pragma unroll
                for (int fc = 0; fc < 2; ++fc)
                    acc[fr][fc] = __builtin_amdgcn_mfma_f32_16x16x32_bf16(af[fr], bfr[fc], acc[fr][fc], 0, 0, 0);
        }
        __syncthreads();
    }
    #pragma unroll
    for (int fr = 0; fr < 2; ++fr)
        #pragma unroll
        for (int fc = 0; fc < 2; ++fc)
            #pragma unroll
            for (int rg = 0; rg < 4; ++rg){
                int i = i0 + wr*32 + fr*16 + (lane >> 4)*4 + rg;
                int j = j0 + wc*32 + fc*16 + (lane & 15);
                float v = acc[fr][fc][rg];
                hi [(size_t)i*LDH + j] = v;
                hib[(size_t)i*LDH + j] = f2b(v);
            }
}

// ---------------- GEMM2 (MFMA, reg-prefetch) + GCNII epilogue; writes bf16-transposed h -----
__global__ __launch_bounds__(256)
void k_layerm(const unsigned short* __restrict__ hib, const unsigned short* __restrict__ h0b,
              const unsigned short* __restrict__ Wt, const float* __restrict__ hi,
              const float* __restrict__ h0, float theta, float cth,
              unsigned short* __restrict__ hT_out)
{
    __shared__ unsigned short sA[64*64], sB[64*64];
    const int i0 = blockIdx.y*64, j0 = blockIdx.x*64;
    const int tid = threadIdx.x, lane = tid & 63, w = tid >> 6;
    const int wr = w >> 1, wc = w & 1;
    const int srow = tid >> 2, scol = (tid & 3) * 16;
    const unsigned short* pa0 = &hib[(size_t)(i0+srow)*LDH + scol];
    const unsigned short* pa1 = &h0b[(size_t)(i0+srow)*LDH + scol];
    const unsigned short* pw  = &Wt [(size_t)(j0+srow)*1024 + scol];
    uint4 a0 = *(const uint4*)(pa0);
    uint4 a1 = *(const uint4*)(pa0 + 8);
    uint4 b0 = *(const uint4*)(pw);
    uint4 b1 = *(const uint4*)(pw + 8);
    f32x4 acc[2][2] = {};
    for (int k0 = 0; k0 < 1024; k0 += 64){
        *(uint4*)&sA[SWZ(srow, scol)]     = a0;
        *(uint4*)&sA[SWZ(srow, scol + 8)] = a1;
        *(uint4*)&sB[SWZ(srow, scol)]     = b0;
        *(uint4*)&sB[SWZ(srow, scol + 8)] = b1;
        int kn = k0 + 64;
        if (kn < 1024){
            const unsigned short* ap = (kn < 512) ? (pa0 + kn) : (pa1 + kn - 512);
            a0 = *(const uint4*)(ap);
            a1 = *(const uint4*)(ap + 8);
            b0 = *(const uint4*)(pw + kn);
            b1 = *(const uint4*)(pw + kn + 8);
        }
        __syncthreads();
        #pragma unroll
        for (int ks = 0; ks < 2; ++ks){
            int kk = ks*32 + (lane >> 4)*8;
            short8 af[2], bfr[2];
            #pragma unroll
            for (int fr = 0; fr < 2; ++fr){
                int r = wr*32 + fr*16 + (lane & 15);
                af[fr] = *(const short8*)&sA[SWZ(r, kk)];
            }
            #pragma unroll
            for (int fc = 0; fc < 2; ++fc){
                int c = wc*32 + fc*16 + (lane & 15);
                bfr[fc] = *(const short8*)&sB[SWZ(c, kk)];
            }
            #pragma unroll
            for (int fr = 0; fr < 2; ++fr)
                #pragma unroll
                for (int fc = 0; fc < 2; ++fc)
                    acc[fr][fc] = __builtin_amdgcn_mfma_f32_16x16x32_bf16(af[fr], bfr[fc], acc[fr][fc], 0, 0, 0);
        }
        __syncthreads();
    }
    #pragma unroll
    for (int fr = 0; fr < 2; ++fr)
        #pragma unroll
        for (int fc = 0; fc < 2; ++fc)
            #pragma unroll
            for (int rg = 0; rg < 4; ++rg){
                int i = i0 + wr*32 + fr*16 + (lane >> 4)*4 + rg;
                int j = j0 + wc*32 + fc*16 + (lane & 15);
                float hv  = hi[(size_t)i*LDH + j];
                float h0v = h0[(size_t)i*LDH + j];
                float o = fmaxf(theta*acc[fr][fc][rg] + cth*(0.9f*hv + 0.1f*h0v), 0.f);
                hT_out[(size_t)j*LDA + i] = f2b(o);
            }
}

// ---------------- final classify + log_softmax (reads bf16-transposed h) ----------------
__global__ void k_final(const unsigned short* __restrict__ hT, const float* __restrict__ Wfc,
                        const float* __restrict__ bfc, float* __restrict__ out, int N)
{
    int i = blockIdx.x, lane = threadIdx.x;  // 64 threads
    float acc[7] = {};
    for (int k = lane; k < 1500; k += 64){
        int m = (k >= 1000) ? 2 : ((k >= 500) ? 1 : 0);
        int kk = k - m*500;
        float f = b2f(hT[(size_t)kk*LDA + m*N + i]);
        f = fmaxf(f, 0.f);
        #pragma unroll
        for (int c = 0; c < 7; ++c) acc[c] += f * Wfc[(size_t)k*7 + c];
    }
    #pragma unroll
    for (int off = 32; off > 0; off >>= 1){
        #pragma unroll
        for (int c = 0; c < 7; ++c) acc[c] += __shfl_down(acc[c], off, 64);
    }
    if (lane == 0){
        float lg[7], mx = -1e30f;
        #pragma unroll
        for (int c = 0; c < 7; ++c){ lg[c] = acc[c] + bfc[c]; mx = fmaxf(mx, lg[c]); }
        float s = 0.f;
        #pragma unroll
        for (int c = 0; c < 7; ++c) s += expf(lg[c] - mx);
        float lse = mx + logf(s);
        #pragma unroll
        for (int c = 0; c < 7; ++c) out[(size_t)i*7 + c] = lg[c] - lse;
    }
}

extern "C" void kernel_launch(void* const* d_in, const int* in_sizes, int n_in,
                              void* d_out, int out_size, void* d_ws, size_t ws_size,
                              hipStream_t stream)
{
    const float* speaker = (const float*)d_in[1];
    const float* fea_a   = (const float*)d_in[2];
    const float* fea_v   = (const float*)d_in[3];
    const float* fea_t   = (const float*)d_in[4];
    const float* Wa      = (const float*)d_in[5];
    const float* ba      = (const float*)d_in[6];
    const float* Wv      = (const float*)d_in[7];
    const float* bv      = (const float*)d_in[8];
    const float* Wt_in   = (const float*)d_in[9];
    const float* bt      = (const float*)d_in[10];
    const float* spk_emb = (const float*)d_in[11];
    const float* W_in    = (const float*)d_in[12];
    const float* b_in    = (const float*)d_in[13];
    const float* W_convs = (const float*)d_in[14];
    const float* W_fc1   = (const float*)d_in[15];
    const float* b_fc1   = (const float*)d_in[16];
    const int* seq = (const int*)d_in[18];
    const int* bat = (const int*)d_in[19];
    const int* dia = (const int*)d_in[20];

    const int N  = in_sizes[18];   // 411
    const int M3 = 3*N;            // 1233

    // ---- workspace layout (byte offsets) ----
    char* wsb = (char*)d_ws;
    float*          Aw   = (float*)(wsb);                               // 6,553,600 B
    unsigned short* Abf  = (unsigned short*)(wsb + 6553600);            // 3,276,800
    float*          x    = (float*)(wsb + 9830400);                     // 1,638,400
    float*          fn   = (float*)(wsb + 11468800);                    // 1,638,400
    float*          h0   = (float*)(wsb + 13107200);                    // 2,621,440
    unsigned short* h0b  = (unsigned short*)(wsb + 15728640);           // 1,310,720
    unsigned short* h0bT = (unsigned short*)(wsb + 17039360);           // 1,310,720
    unsigned short* hTa  = (unsigned short*)(wsb + 18350080);           // 1,310,720
    unsigned short* hTb  = (unsigned short*)(wsb + 19660800);           // 1,310,720
    float*          hi   = (float*)(wsb + 20971520);                    // 2,621,440
    unsigned short* hib  = (unsigned short*)(wsb + 23592960);           // 1,310,720
    unsigned short* Wt   = (unsigned short*)(wsb + 24903680);           // 8,388,608 (8 slots)
    float*          dinv = (float*)(wsb + 33292288);                    // 5,120
    float*          xga  = (float*)(wsb + 33297408);                    // 2,867,200
    float*          xgv  = (float*)(wsb + 36164608);                    // 688,128
    float*          xgt  = (float*)(wsb + 36852736);                    // 1,835,008
    int*            spki = (int*)(wsb + 38687744);                      // 1,792
    // prologue-only scratch ALIASED onto {hi, hib, Wt} (dead before first k_spmm/k_wtr):
    float*          WaT  = (float*)(wsb + 20971520);                    // 300*1600*4 = 1,920,000
    float*          WvT  = (float*)(wsb + 22891520);                    // 300*384*4  =   460,800
    float*          WtT  = (float*)(wsb + 23352320);                    // 300*1024*4 = 1,228,800
    float*          xpa  = (float*)(wsb + 24581120);                    // 4*448*320*4 = 2,293,760
    float*          xpv  = (float*)(wsb + 26874880);                    // 2*448*320*4 = 1,146,880
    float*          xpt  = (float*)(wsb + 28021760);                    // 4*448*320*4 = 2,293,760 (ends 30,315,520)

    hipMemsetAsync(Aw,  0, 6553600, stream);
    hipMemsetAsync(Abf, 0, 3276800, stream);
    hipMemsetAsync(x,   0, 1638400, stream);
    hipMemsetAsync(fn,  0, 1638400, stream);

    k_gather<<<448, 256, 0, stream>>>(fea_a, fea_v, fea_t, speaker, seq, bat, xga, xgv, xgt, spki, N);

    k_trw<<<dim3(25, 5), 256, 0, stream>>>(Wa,    1582, 1600, WaT);
    k_trw<<<dim3( 6, 5), 256, 0, stream>>>(Wv,     342,  384, WvT);
    k_trw<<<dim3(16, 5), 256, 0, stream>>>(Wt_in, 1024, 1024, WtT);

    k_projg2<<<dim3(5, 7, 4), 256, 0, stream>>>(xga, 1600, 400, WaT, xpa);
    k_projg2<<<dim3(5, 7, 2), 256, 0, stream>>>(xgv,  384, 192, WvT, xpv);
    k_projg2<<<dim3(5, 7, 4), 256, 0, stream>>>(xgt, 1024, 256, WtT, xpt);

    k_norm2<<<M3, 256, 0, stream>>>(xpa, xpv, xpt, ba, bv, bt, spk_emb, spki, x, fn, N);

    int nt = (N + 31)/32;
    k_intra<<<dim3(nt, nt, 3), dim3(16,16), 0, stream>>>(fn, dia, Aw, N);
    k_cross<<<N, 64, 0, stream>>>(fn, Aw, N);
    k_rowsum<<<M3, 256, 0, stream>>>(Aw, dinv, M3);
    k_scale<<<dim3((M3+15)/16, (M3+15)/16), dim3(16,16), 0, stream>>>(Aw, Abf, dinv, M3);

    k_gemm_h0<<<dim3(8, 20), 256, 0, stream>>>(x, W_in, b_in, h0, h0b, h0bT, M3);

    const unsigned short* curT = h0bT;
    unsigned short* pp[2] = {hTa, hTb};
    for (int l = 1; l <= 64; ++l){
        if (((l-1) & 7) == 0)
            k_wtr<<<dim3(16, 8, 8), 256, 0, stream>>>(W_convs, (l-1) >> 3, Wt);
        k_spmm<<<dim3(8, 20), 256, 0, stream>>>(Abf, curT, hi, hib);
        float th = logf(0.5f/(float)l + 1.0f);
        unsigned short* o = pp[(l-1) & 1];
        k_layerm<<<dim3(8, 20), 256, 0, stream>>>(hib, h0b, Wt + (size_t)((l-1) & 7)*LDH*1024,
                                                  hi, h0, th, 1.0f - th, o);
        curT = o;
    }

    k_final<<<N, 64, 0, stream>>>(curT, W_fc1, b_fc1, (float*)d_out, N);
}